// Round 1
// baseline (123.703 us; speedup 1.0000x reference)
//
#include <hip/hip_runtime.h>

// Problem constants (from the JAX reference):
//   inputs: (B=128, T=2048, C=66) f32; tensors = [:, :, 0:64], indicator = [:, :, 64]
//   WINDOW=16, STRIDES=1 -> starts = 0..2032 (S=2033)
//   out[b, f, s] = sum_{t=s..s+15} x[b,t,f]*ind[b,t] / (sum |x[b,t,f]| + 1e-5)
#define B_   128
#define T_   2048
#define C_   66
#define F_   64
#define W_   16
#define S_   2033
#define SBLK 64
#define TILE_T 80           // SBLK - 1 + W = 79, rounded to 80 so tile floats % 4 == 0
#define EPS_ 1e-5f

__global__ __launch_bounds__(256)
void ts_pct_kernel(const float* __restrict__ in, float* __restrict__ out) {
    __shared__ float lds [TILE_T * C_];        // 80*66*4   = 21120 B  (input tile)
    __shared__ float lout[F_ * (SBLK + 1)];    // 64*65*4   = 16640 B  (padded out tile)

    const int tid = threadIdx.x;
    const int b   = blockIdx.x;
    const int sb  = blockIdx.y;
    const int t0  = sb * SBLK;                 // first start index of this block

    // ---- Stage input tile [t0, t0+80) x 66 into LDS, coalesced float4 ----
    const float*  src  = in + (size_t)b * (T_ * C_) + (size_t)t0 * C_;
    const float4* src4 = (const float4*)src;   // t0*C_ = sb*4224, %4==0 -> 16B aligned
    float4*       l4   = (float4*)lds;
    const int nvalid4  = (min(TILE_T, T_ - t0) * C_) >> 2;   // both cases divisible by 4
    #pragma unroll
    for (int i = tid; i < (TILE_T * C_) / 4; i += 256) {
        l4[i] = (i < nvalid4) ? src4[i] : make_float4(0.f, 0.f, 0.f, 0.f);
    }
    __syncthreads();

    // ---- Compute: thread = (f = lane, sq = wave), 16 outputs each ----
    const int f  = tid & 63;
    const int sq = tid >> 6;
    const int tb = sq * 16;                    // local row offset of first window

    float sp = 0.f, sa = 0.f;
    float vp[W_], va[W_];                      // static-indexed only (full unroll)
    float r[16];

    #pragma unroll
    for (int i = 0; i < W_; ++i) {
        const float x   = lds[(tb + i) * C_ + f];
        const float ind = lds[(tb + i) * C_ + 64];
        const float p = x * ind;
        const float a = fabsf(x);
        sp += p; sa += a;
        vp[i] = p; va[i] = a;
    }
    r[0] = sp / (sa + EPS_);

    #pragma unroll
    for (int i = 1; i < 16; ++i) {
        const float x   = lds[(tb + 15 + i) * C_ + f];
        const float ind = lds[(tb + 15 + i) * C_ + 64];
        const float p = x * ind;
        const float a = fabsf(x);
        sp += p - vp[i - 1];
        sa += a - va[i - 1];
        r[i] = sp / (sa + EPS_);
    }

    // ---- Transpose through LDS (pad 65 -> (65f + j) % 32 spreads banks) ----
    #pragma unroll
    for (int i = 0; i < 16; ++i)
        lout[f * (SBLK + 1) + tb + i] = r[i];
    __syncthreads();

    // ---- Coalesced store: each wave writes one full 256B row segment ----
    float* dst = out + (size_t)b * (F_ * S_) + t0;
    #pragma unroll
    for (int k = 0; k < 16; ++k) {
        const int idx = tid + k * 256;         // 4096 = 64 rows x 64 cols
        const int f2  = idx >> 6;
        const int j   = idx & 63;
        if (t0 + j < S_)
            dst[(size_t)f2 * S_ + j] = lout[f2 * (SBLK + 1) + j];
    }
}

extern "C" void kernel_launch(void* const* d_in, const int* in_sizes, int n_in,
                              void* d_out, int out_size, void* d_ws, size_t ws_size,
                              hipStream_t stream) {
    const float* in = (const float*)d_in[0];
    float* out = (float*)d_out;
    dim3 grid(B_, (S_ + SBLK - 1) / SBLK);     // (128, 32)
    ts_pct_kernel<<<grid, 256, 0, stream>>>(in, out);
}

// Round 2
// 119.337 us; speedup vs baseline: 1.0366x; 1.0366x over previous
//
#include <hip/hip_runtime.h>

// inputs: (B=128, T=2048, C=66) f32; x = [:,:,0:64], ind = [:,:,64]
// out[b,f,s] = sum_{t=s..s+15} x[b,t,f]*ind[b,t] / (sum_{t} |x[b,t,f]| + 1e-5)
// out shape (B, 64, 2033)
#define B_    128
#define T_    2048
#define C_    66
#define F_    64
#define W_    16
#define S_    2033
#define SBLK  128
#define NTHR  512
#define TILE_T 144          // SBLK - 1 + W = 143, rounded so tile floats % 4 == 0
#define EPS_  1e-5f

// Union LDS buffer: input tile (144*66 = 9504 f = 38016 B) reused as the
// padded output-transpose tile (64*129 = 8256 f = 33024 B). 38 KB -> 4
// blocks/CU -> 32 waves/CU (full occupancy).
__global__ __launch_bounds__(NTHR)
void ts_pct_kernel(const float* __restrict__ in, float* __restrict__ out) {
    __shared__ float lds[TILE_T * C_];

    const int tid = threadIdx.x;
    const int b   = blockIdx.x;
    const int sb  = blockIdx.y;
    const int t0  = sb * SBLK;

    // ---- Stage input tile [t0, t0+144) x 66, coalesced float4 ----
    const float4* src4 = (const float4*)(in + (size_t)b * (T_ * C_) + (size_t)t0 * C_);
    float4*       l4   = (float4*)lds;
    const int nvalid4  = (min(TILE_T, T_ - t0) * C_) >> 2;   // divisible by 4 either way
    #pragma unroll
    for (int i = tid; i < (TILE_T * C_) / 4; i += NTHR) {
        l4[i] = (i < nvalid4) ? src4[i] : make_float4(0.f, 0.f, 0.f, 0.f);
    }
    __syncthreads();

    // ---- Compute: thread = (f = lane, sq = wave), 16 outputs each ----
    const int f  = tid & 63;
    const int sq = tid >> 6;                  // 0..7
    const int tb = sq * 16;

    float sp = 0.f, sa = 0.f;
    float vp[W_], va[W_];                     // static-indexed only (fully unrolled)
    float r[16];

    #pragma unroll
    for (int i = 0; i < W_; ++i) {
        const float x   = lds[(tb + i) * C_ + f];
        const float ind = lds[(tb + i) * C_ + 64];   // wave-uniform -> broadcast
        const float p = x * ind;
        const float a = fabsf(x);
        sp += p; sa += a;
        vp[i] = p; va[i] = a;
    }
    r[0] = sp * __builtin_amdgcn_rcpf(sa + EPS_);

    #pragma unroll
    for (int i = 1; i < 16; ++i) {
        const float x   = lds[(tb + 15 + i) * C_ + f];
        const float ind = lds[(tb + 15 + i) * C_ + 64];
        const float p = x * ind;
        const float a = fabsf(x);
        sp += p - vp[i - 1];
        sa += a - va[i - 1];
        r[i] = sp * __builtin_amdgcn_rcpf(sa + EPS_);
    }
    __syncthreads();                          // tile reads done; safe to overwrite

    // ---- Transpose via LDS (row pad 129 floats kills bank conflicts) ----
    #pragma unroll
    for (int i = 0; i < 16; ++i)
        lds[f * (SBLK + 1) + tb + i] = r[i];
    __syncthreads();

    // ---- Coalesced store: each wave writes 256B runs of one f row ----
    float* dst = out + (size_t)b * (F_ * S_) + t0;
    if (t0 + SBLK <= S_) {                    // uniform: all but last s-block
        #pragma unroll
        for (int k = 0; k < (F_ * SBLK) / NTHR; ++k) {
            const int idx = tid + k * NTHR;
            const int f2  = idx >> 7;
            const int j   = idx & 127;
            dst[(size_t)f2 * S_ + j] = lds[f2 * (SBLK + 1) + j];
        }
    } else {
        #pragma unroll
        for (int k = 0; k < (F_ * SBLK) / NTHR; ++k) {
            const int idx = tid + k * NTHR;
            const int f2  = idx >> 7;
            const int j   = idx & 127;
            if (t0 + j < S_)
                dst[(size_t)f2 * S_ + j] = lds[f2 * (SBLK + 1) + j];
        }
    }
}

extern "C" void kernel_launch(void* const* d_in, const int* in_sizes, int n_in,
                              void* d_out, int out_size, void* d_ws, size_t ws_size,
                              hipStream_t stream) {
    const float* in = (const float*)d_in[0];
    float* out = (float*)d_out;
    dim3 grid(B_, (S_ + SBLK - 1) / SBLK);    // (128, 16)
    ts_pct_kernel<<<grid, NTHR, 0, stream>>>(in, out);
}

// Round 3
// 119.069 us; speedup vs baseline: 1.0389x; 1.0023x over previous
//
#include <hip/hip_runtime.h>

// inputs: (B=128, T=2048, C=66) f32; x = [:,:,0:64], ind = [:,:,64]
// out[b,f,s] = sum_{t=s..s+15} x[b,t,f]*ind[b,t] / (sum_t |x[b,t,f]| + 1e-5)
// out shape (B, 64, 2033)
#define B_    128
#define T_    2048
#define C_    66
#define F_    64
#define W_    16
#define S_    2033
#define SBLK  128
#define NTHR  512
#define EPS_  1e-5f

// No input staging: with thread=(f=lane, window-group=wave) each global load
// is a contiguous 256B/wave transaction already; halo reuse across waves and
// blocks is served by L1/L2/L3 (input is 69 MB, fully L3-resident; FETCH_SIZE
// counts HBM only). LDS holds only the 64x129 padded output-transpose tile
// (33 KB -> 4 blocks/CU), one barrier total.
__global__ __launch_bounds__(NTHR)
void ts_pct_kernel(const float* __restrict__ in, float* __restrict__ out) {
    __shared__ float lout[F_ * (SBLK + 1)];   // 64*129*4 = 33024 B

    const int tid = threadIdx.x;
    const int b   = blockIdx.x;
    const int t0  = blockIdx.y * SBLK;
    const int f   = tid & 63;
    const int sq  = tid >> 6;                 // 0..7
    const int tb  = sq * 16;                  // local offset of first window
    const int r0  = t0 + tb;                  // first global row

    const float* bp = in + (size_t)b * (T_ * C_);

    float vp[W_], va[W_];                     // static-indexed only (full unroll)
    float sp = 0.f, sa = 0.f;

    #pragma unroll
    for (int i = 0; i < W_; ++i) {
        const int rc = min(r0 + i, T_ - 1);   // clamp: tail block reads stay in-bounds
        const float x   = bp[rc * C_ + f];    // lanes 0..63 -> 256B coalesced
        const float ind = bp[rc * C_ + 64];   // wave-uniform -> single request
        const float p = x * ind;
        const float a = fabsf(x);
        sp += p; sa += a;
        vp[i] = p; va[i] = a;
    }
    lout[f * (SBLK + 1) + tb] = sp * __builtin_amdgcn_rcpf(sa + EPS_);

    #pragma unroll
    for (int i = 1; i < 16; ++i) {
        const int rc = min(r0 + 15 + i, T_ - 1);
        const float x   = bp[rc * C_ + f];
        const float ind = bp[rc * C_ + 64];
        const float p = x * ind;
        const float a = fabsf(x);
        sp += p - vp[i - 1];
        sa += a - va[i - 1];
        lout[f * (SBLK + 1) + tb + i] = sp * __builtin_amdgcn_rcpf(sa + EPS_);
    }
    __syncthreads();

    // Coalesced store: each wave writes contiguous 512B runs of one f row.
    float* dst = out + (size_t)b * (F_ * S_) + t0;
    if (t0 + SBLK <= S_) {                    // uniform branch: all but last s-block
        #pragma unroll
        for (int k = 0; k < (F_ * SBLK) / NTHR; ++k) {
            const int idx = tid + k * NTHR;
            const int f2  = idx >> 7;
            const int j   = idx & 127;
            dst[(size_t)f2 * S_ + j] = lout[f2 * (SBLK + 1) + j];
        }
    } else {
        #pragma unroll
        for (int k = 0; k < (F_ * SBLK) / NTHR; ++k) {
            const int idx = tid + k * NTHR;
            const int f2  = idx >> 7;
            const int j   = idx & 127;
            if (t0 + j < S_)
                dst[(size_t)f2 * S_ + j] = lout[f2 * (SBLK + 1) + j];
        }
    }
}

extern "C" void kernel_launch(void* const* d_in, const int* in_sizes, int n_in,
                              void* d_out, int out_size, void* d_ws, size_t ws_size,
                              hipStream_t stream) {
    const float* in = (const float*)d_in[0];
    float* out = (float*)d_out;
    dim3 grid(B_, (S_ + SBLK - 1) / SBLK);    // (128, 16)
    ts_pct_kernel<<<grid, NTHR, 0, stream>>>(in, out);
}